// Round 1
// 333.703 us; speedup vs baseline: 1.0272x; 1.0272x over previous
//
#include <hip/hip_runtime.h>
#include <hip/hip_bf16.h>

#define M_DIM 64
#define K_DIM 4096
#define N_DIM 14336
#define NBLKS 224       // one block per 64 n-cols
#define KW 512          // k-range per wave (8 waves cover K=4096)
#define WCHUNKS 16      // 32-k chunks per wave

typedef __attribute__((ext_vector_type(8))) short bf16x8;
typedef __attribute__((ext_vector_type(4))) float f32x4;
typedef unsigned short u16;

// ---------------------------------------------------------------------------
// prep: split x (fp32) into bf16 hi/lo in MFMA-A-fragment layout
// (elem idx = (k/8)*(64*8) + m*8 + (k%8)), with rowsum fused in.
// 64 blocks (one per m-row) x 512 threads (one 8-k group per thread).
__global__ __launch_bounds__(512) void prep_split(
    const float* __restrict__ x, u16* __restrict__ xh, u16* __restrict__ xl,
    float* __restrict__ rs) {
  const int m = blockIdx.x;
  const int t = threadIdx.x;  // kb = t, 0..511
  const float* xp = x + m * K_DIM + t * 8;
  u16 hs[8], ls[8];
  float s = 0.f;
#pragma unroll
  for (int j = 0; j < 8; ++j) {
    float v = xp[j];
    s += v;
    unsigned hv = __float_as_uint(v) & 0xFFFF0000u;  // bf16 truncate (exact)
    float r = v - __uint_as_float(hv);
    hs[j] = (u16)(hv >> 16);
    ls[j] = (u16)(__float_as_uint(r) >> 16);
  }
  int o = t * (M_DIM * 8) + m * 8;
  *(uint4*)(xh + o) = *(uint4*)hs;
  *(uint4*)(xl + o) = *(uint4*)ls;
  // fused rowsum: block-reduce the 512 per-thread partials
#pragma unroll
  for (int off = 32; off > 0; off >>= 1) s += __shfl_down(s, off, 64);
  __shared__ float red[8];
  if ((t & 63) == 0) red[t >> 6] = s;
  __syncthreads();
  if (t == 0) {
    float a = 0.f;
#pragma unroll
    for (int i = 0; i < 8; ++i) a += red[i];
    rs[m] = a;
  }
}

// ---------------------------------------------------------------------------
// Streaming GEMM v6 — zero auxiliary global traffic (unchanged), but 8 waves
// per block (2/SIMD) instead of 4 (1/SIMD). R8 theory: with 1 wave/SIMD the
// per-chunk issue stream (~750 cyc) is shorter than the depth-1 prefetch's
// HBM latency (~900 cyc) -> per-chunk vmcnt stall with no co-resident wave
// to hide it. 2 waves/SIMD interleave: one drains vmcnt while the sibling
// issues MFMAs; per-CU outstanding bytes double. K-reduction is two-stage in
// the same 67.6 KB LDS buffer (waves 0-3 deposit, waves 4-7 RMW-accumulate).
__global__ __launch_bounds__(512, 2) void wqmm(
    const int* __restrict__ W, const u16* __restrict__ xh,
    const u16* __restrict__ xl, const float* __restrict__ rowsum,
    const float* __restrict__ scale, const float* __restrict__ offset,
    const float* __restrict__ bias, float* __restrict__ out) {
  __shared__ __align__(16) float red[4][64][66];  // 67.6 KB, 2-way max

  const int t = threadIdx.x;
  const int lane = t & 63;
  const int wv = t >> 6;       // k-eighth, 0..7
  const int quad = lane >> 4;
  const int lnk = lane & 15;
  const int nbase = blockIdx.x * 64;
  const int k0 = wv * KW;

  // loop-invariant per-lane dword offsets into W
  int laneoff[4];
#pragma unroll
  for (int f = 0; f < 4; ++f)
    laneoff[f] = quad * 8 * N_DIM + nbase + lnk + f * 16;

  const u16* xhp = xh + (size_t)(wv * 64 + quad) * 512 + lnk * 8;
  const u16* xlp = xl + (size_t)(wv * 64 + quad) * 512 + lnk * 8;

  f32x4 acc[4][4] = {};       // [m-tile][n-frag]
  int raw[2][4][8];           // W double buffer (literal indices only)
  bf16x8 abh[2][4], abl[2][4];  // A double buffer

#define LOADW(CC, BUF)                                            \
  do {                                                            \
    _Pragma("unroll") for (int j = 0; j < 8; ++j) {               \
      const int* bj = W + (size_t)(k0 + (CC) * 32 + j) * N_DIM;   \
      _Pragma("unroll") for (int f = 0; f < 4; ++f)               \
          raw[BUF][f][j] = bj[laneoff[f]];                        \
    }                                                             \
  } while (0)

#define LOADA(CC, BUF)                                            \
  do {                                                            \
    const u16* ahc = xhp + (CC) * 2048;                           \
    const u16* alc = xlp + (CC) * 2048;                           \
    _Pragma("unroll") for (int mt = 0; mt < 4; ++mt) {            \
      abh[BUF][mt] = *(const bf16x8*)(ahc + mt * 128);            \
      abl[BUF][mt] = *(const bf16x8*)(alc + mt * 128);            \
    }                                                             \
  } while (0)

#define COMPUTE(CC, BUF)                                                     \
  do {                                                                       \
    bf16x8 bfr[4];                                                           \
    _Pragma("unroll") for (int f = 0; f < 4; ++f) {                          \
      union {                                                                \
        int i4[4];                                                           \
        bf16x8 v;                                                            \
      } u;                                                                   \
      _Pragma("unroll") for (int wd = 0; wd < 4; ++wd) {                     \
        unsigned lo = __float_as_uint((float)raw[BUF][f][2 * wd]);           \
        unsigned hi = __float_as_uint((float)raw[BUF][f][2 * wd + 1]);       \
        /* v_perm_b32: D = {hi[31:16], lo[31:16]} — exact bf16 pack */       \
        u.i4[wd] = (int)__builtin_amdgcn_perm(hi, lo, 0x07060302u);          \
      }                                                                      \
      bfr[f] = u.v;                                                          \
    }                                                                        \
    _Pragma("unroll") for (int mt = 0; mt < 4; ++mt) {                       \
      _Pragma("unroll") for (int f = 0; f < 4; ++f) {                        \
        acc[mt][f] = __builtin_amdgcn_mfma_f32_16x16x32_bf16(                \
            abh[BUF][mt], bfr[f], acc[mt][f], 0, 0, 0);                      \
        acc[mt][f] = __builtin_amdgcn_mfma_f32_16x16x32_bf16(                \
            abl[BUF][mt], bfr[f], acc[mt][f], 0, 0, 0);                      \
      }                                                                      \
    }                                                                        \
  } while (0)

  LOADW(0, 0);
  LOADA(0, 0);
  for (int c = 0; c < WCHUNKS; c += 2) {  // literal buffer indices in body
    LOADW(c + 1, 1);
    LOADA(c + 1, 1);
    COMPUTE(c, 0);
    if (c + 2 < WCHUNKS) {
      LOADW(c + 2, 0);
      LOADA(c + 2, 0);
    }
    COMPUTE(c + 1, 1);
  }
#undef LOADW
#undef LOADA
#undef COMPUTE

  // two-stage intra-block k-reduction in 67.6 KB:
  // stage 1: waves 0-3 deposit their 64x64 tile
  if (wv < 4) {
#pragma unroll
    for (int f = 0; f < 4; ++f)
#pragma unroll
      for (int mt = 0; mt < 4; ++mt)
#pragma unroll
        for (int r = 0; r < 4; ++r)
          red[wv][mt * 16 + quad * 4 + r][f * 16 + lnk] = acc[mt][f][r];
  }
  __syncthreads();
  // stage 2: waves 4-7 accumulate into the matching buffer (disjoint addrs)
  if (wv >= 4) {
#pragma unroll
    for (int f = 0; f < 4; ++f)
#pragma unroll
      for (int mt = 0; mt < 4; ++mt)
#pragma unroll
        for (int r = 0; r < 4; ++r)
          red[wv - 4][mt * 16 + quad * 4 + r][f * 16 + lnk] += acc[mt][f][r];
  }
  __syncthreads();

  // fused epilogue: out = scale*sum + scale*offset*rowsum[m] + bias
#pragma unroll
  for (int i = 0; i < 8; ++i) {
    int idx = t + i * 512;  // linear over 64x64 tile -> coalesced stores
    int m = idx >> 6;
    int nc = idx & 63;
    float s = red[0][m][nc] + red[1][m][nc] + red[2][m][nc] + red[3][m][nc];
    int n = nbase + nc;
    float sc = scale[n];
    out[(size_t)m * N_DIM + n] = s * sc + sc * offset[n] * rowsum[m] + bias[n];
  }
}

extern "C" void kernel_launch(void* const* d_in, const int* in_sizes, int n_in,
                              void* d_out, int out_size, void* d_ws,
                              size_t ws_size, hipStream_t stream) {
  const float* x = (const float*)d_in[0];
  const int* W = (const int*)d_in[1];
  const float* scale = (const float*)d_in[2];
  const float* offset = (const float*)d_in[3];
  const float* bias = (const float*)d_in[4];
  float* out = (float*)d_out;

  char* wsb = (char*)d_ws;
  u16* xh = (u16*)wsb;                          // 512 KB
  u16* xl = xh + (size_t)M_DIM * K_DIM;         // 512 KB
  float* rowsum = (float*)(xl + (size_t)M_DIM * K_DIM);

  prep_split<<<64, 512, 0, stream>>>(x, xh, xl, rowsum);
  wqmm<<<NBLKS, 512, 0, stream>>>(W, xh, xl, rowsum, scale, offset, bias, out);
}